// Round 13
// baseline (98.447 us; speedup 1.0000x reference)
//
#include <hip/hip_runtime.h>
#include <stdint.h>

#pragma clang fp contract(off)

#define NMS_B 8
#define NMS_N 4096
#define ROIS 256
#define SEL_TAU 0.85f

typedef unsigned long long u64;
typedef unsigned int u32;

__device__ __forceinline__ int lds_slot(int e) { return e + (e >> 2); }  // 4-way max bank aliasing

__device__ __forceinline__ u64 rdlane_u64(u64 v, int l) {
    u32 lo = (u32)__builtin_amdgcn_readlane((int)(u32)v, l);
    u32 hi = (u32)__builtin_amdgcn_readlane((int)(u32)(v >> 32), l);
    return ((u64)hi << 32) | lo;
}

// suppression predicate (exact arithmetic of the proven K2):
// true => row box suppresses col box (IoU > 0.5); symmetric.
__device__ __forceinline__ bool sup_pred(float4 rc, float rh, float4 cc, float ch) {
    float iw = fmaxf(fminf(rc.z, cc.z) - fmaxf(rc.x, cc.x), 0.0f);
    float ih = fmaxf(fminf(rc.w, cc.w) - fmaxf(rc.y, cc.y), 0.0f);
    float inter = iw * ih;
    return inter > fmaf(-0.5f, inter, rh + ch);   // 1.5*inter > haR+haC
}

// ---------------------------------------------------------------------------
// v15: last-block-does-scan. v14 accounting: kernels+gaps ~45us; K3 existed
// only to reload h and run a 7us 1-wave scan (launch gap + startup + reload
// on the critical path). v15: K2 -> 18 blocks/batch (1 task/wave, E
// halves); after h-writes, threadfence + atomicAdd(done[b]); the block
// seeing old==17 reloads h and runs scan+output INSIDE K2's dispatch.
// Scan chain trimmed: kept-recording via kb bitmap + popcount-prefix
// expansion after the loop (bit-identical: ctz takes ascending r).
// Exactness: K1 inlines the full v8 fallback (selection out of range);
// K3 is fallback-only (no-op unless scan found <256 in 512 rows).
// ---------------------------------------------------------------------------

// K1: select (tau) + bitonic-1024 + corners for top-512 -> workspace.
// Inline full v8 fallback when selection is out of range.
__global__ __launch_bounds__(1024, 1) void nms_k1(
        const float* __restrict__ in, float4* __restrict__ crn512,
        float* __restrict__ ha512, u32* __restrict__ sidx512,
        int* __restrict__ flag, int* __restrict__ done, int* __restrict__ needFull,
        u32* __restrict__ sortedIdx, float4* __restrict__ crn,
        float* __restrict__ ha, float* __restrict__ outp) {
    __shared__ u64 sm[5120];                 // 40 KB: sel/sort fast path, v8 arena full path
    __shared__ int kept[ROIS];
    __shared__ int s_selCount;
    const int b = blockIdx.x, t = threadIdx.x;
    const int lane = t & 63, wid = t >> 6;
    const size_t base = (size_t)b * NMS_N;

    u64* selKey = sm;                        // [1024]
    u64* sortA0 = sm + 1024;                 // [1280]
    u64* sortA1 = sm + 2304;                 // [1280]

    // A: load scores; zero cross-kernel state
    float sc[4];
    #pragma unroll
    for (int r = 0; r < 4; ++r) {
        int e = t + 1024 * r;
        sc[r] = in[(base + e) * 5];
    }
    if (t == 0) { s_selCount = 0; done[b] = 0; needFull[b] = 0; }
    __syncthreads();

    // B: wave-aggregated selection append (score >= tau)
    #pragma unroll
    for (int r = 0; r < 4; ++r) {
        bool pred = (sc[r] >= SEL_TAU);
        u64 m = __ballot(pred);
        u32 cnt = (u32)__popcll(m);
        int wbase = 0;
        if (lane == 0 && cnt) wbase = atomicAdd(&s_selCount, (int)cnt);
        wbase = __shfl(wbase, 0, 64);
        if (pred) {
            int slot = wbase + (int)__popcll(m & ((1ULL << lane) - 1ULL));
            if (slot < 1024) {
                int e = t + 1024 * r;
                selKey[slot] = ((u64)(~__float_as_uint(sc[r])) << 32) | (u32)e;
            }
        }
    }
    __syncthreads();
    const int selCount = s_selCount;
    const bool fullPath = (selCount < 512) || (selCount > 1024);   // uniform
    if (t == 0) flag[b] = fullPath ? 1 : 0;

    if (!fullPath) {
        // C: bitonic 1024, 1 elem/thread, double-buffered LDS (bit-identical)
        u64 kk = (t < selCount) ? selKey[t] : ~0ULL;   // pad sorts to end
        int s = 0;
        for (int k = 2; k <= 1024; k <<= 1) {
            int j = k >> 1;
            for (; j >= 64; j >>= 1) {
                u64* buf = s ? sortA1 : sortA0;
                buf[lds_slot(t)] = kk;
                __syncthreads();             // RAW only; WAR killed by dbuf
                u64 part = buf[lds_slot(t ^ j)];
                bool up = ((t & k) == 0), lower = ((t & j) == 0);
                u64 mn = kk < part ? kk : part, mx = kk < part ? part : kk;
                kk = (up == lower) ? mn : mx;
                s ^= 1;
            }
            for (; j >= 1; j >>= 1) {
                u64 part = __shfl_xor(kk, j, 64);
                bool up = ((t & k) == 0), lower = ((t & j) == 0);
                u64 mn = kk < part ? kk : part, mx = kk < part ? part : kk;
                kk = (up == lower) ? mn : mx;
            }
        }
        // D: corners for top-512 -> workspace (coalesced stores)
        if (t < 512) {
            u32 orig = (u32)kk;
            const float* bp = in + (base + orig) * 5;
            float x = bp[1], y = bp[2], w = bp[3], h = bp[4];
            float ws_ = floorf(w * 0.5f), hs_ = floorf(h * 0.5f);
            float4 c4 = make_float4(x - ws_, y - hs_, x + ws_, y + hs_);
            size_t g = (size_t)b * 512 + t;
            crn512[g] = c4;
            ha512[g] = 0.5f * ((c4.z - c4.x) * (c4.w - c4.y));  // exact half-area
            sidx512[g] = orig;
        }
        return;
    }

    // ======== FULL FALLBACK (v8 verbatim; never on bench data) ========
    {
        u64 key[4];
        #pragma unroll
        for (int r = 0; r < 4; ++r) {
            int e = 4 * t + r;
            float s = in[(base + e) * 5];
            key[r] = ((u64)(~__float_as_uint(s)) << 32) | (u32)e;
        }
        for (int k = 2; k <= 4096; k <<= 1) {
            int j = k >> 1;
            if (j >= 256) {
                #pragma unroll
                for (int r = 0; r < 4; ++r) sm[lds_slot(4 * t + r)] = key[r];
                __syncthreads();
                for (; j >= 256; j >>= 1) {
                    for (int el = t; el < 4096; el += 1024) {
                        int p = el ^ j;
                        if (p > el) {
                            u64 a = sm[lds_slot(el)], cc = sm[lds_slot(p)];
                            bool up = ((el & k) == 0);
                            if ((a > cc) == up) { sm[lds_slot(el)] = cc; sm[lds_slot(p)] = a; }
                        }
                    }
                    __syncthreads();
                }
                #pragma unroll
                for (int r = 0; r < 4; ++r) key[r] = sm[lds_slot(4 * t + r)];
            }
            for (; j >= 4; j >>= 1) {
                int d = j >> 2;
                #pragma unroll
                for (int r = 0; r < 4; ++r) {
                    int e = 4 * t + r;
                    u64 mine = key[r];
                    u64 part = __shfl_xor(mine, d, 64);
                    bool up = ((e & k) == 0);
                    bool lower = ((e & j) == 0);
                    u64 mn = (mine < part) ? mine : part;
                    u64 mx = (mine < part) ? part : mine;
                    key[r] = (up == lower) ? mn : mx;
                }
            }
            for (; j >= 1; j >>= 1) {
                #pragma unroll
                for (int r = 0; r < 4; ++r) {
                    int pr = r | j;
                    if (((r & j) == 0) && pr < 4) {
                        int e = 4 * t + r;
                        bool up = ((e & k) == 0);
                        u64 a = key[r], cc = key[pr];
                        if ((a > cc) == up) { key[r] = cc; key[pr] = a; }
                    }
                }
            }
        }
        __syncthreads();

        u64*    h2 = sm;                      // [36][64]
        float4* crn2 = (float4*)(sm + 2304);  // [512]
        float*  ha2  = (float*)(sm + 2304 + 1024);

        #pragma unroll
        for (int r = 0; r < 4; ++r) {
            int e = 4 * t + r;
            u32 orig = (u32)key[r];
            const float* bp = in + (base + orig) * 5;
            float x = bp[1], y = bp[2], w = bp[3], h = bp[4];
            float ws_ = floorf(w * 0.5f), hs_ = floorf(h * 0.5f);
            float4 c4 = make_float4(x - ws_, y - hs_, x + ws_, y + hs_);
            float hv = 0.5f * ((c4.z - c4.x) * (c4.w - c4.y));
            size_t g = base + e;
            sortedIdx[g] = orig;
            crn[g] = c4;
            ha[g] = hv;
            if (e < 512) { crn2[e] = c4; ha2[e] = hv; }
        }
        for (int r = t; r < ROIS; r += 1024) kept[r] = 0;
        __syncthreads();

        for (int u = wid; u < 36; u += 16) {
            int kr = 0;
            while ((kr + 1) * (kr + 2) / 2 <= u) ++kr;
            int w = u - kr * (kr + 1) / 2;
            float4 myc = crn2[64 * kr + lane];
            float  myh = ha2[64 * kr + lane];
            u64 word = 0;
            #pragma unroll 4
            for (int q = 0; q < 64; ++q) {
                bool p = sup_pred(crn2[64 * w + q], ha2[64 * w + q], myc, myh);
                word |= ((u64)(p ? 1u : 0u)) << q;
            }
            h2[(size_t)u * 64 + lane] = word;
        }
        __syncthreads();

        if (t < 64) {
            int count = 0;
            u32 f[8];
            #pragma unroll
            for (int k = 0; k < 8; ++k) f[k] = 1u;
            bool done_ = false;
            #pragma unroll
            for (int g = 0; g < 8; ++g) {
                if (!done_) {
                    u64 hgg = h2[(size_t)(g * (g + 1) / 2 + g) * 64 + lane];
                    u64 kb = 0;
                    u64 avail = __ballot(f[g] != 0);
                    while (avail != 0 && count < ROIS) {
                        int r = __builtin_ctzll(avail);
                        if (lane == 0) kept[count] = g * 64 + r;
                        ++count;
                        kb |= 1ULL << r;
                        u32 bit = (u32)(hgg >> r) & 1u;
                        f[g] &= (bit ^ 1u) & (u32)(lane != r);
                        avail = __ballot(f[g] != 0);
                    }
                    if (count >= ROIS) {
                        done_ = true;
                    } else {
                        #pragma unroll
                        for (int k2 = g + 1; k2 < 8; ++k2)
                            f[k2] &= (u32)((h2[(size_t)(k2 * (k2 + 1) / 2 + g) * 64 + lane] & kb) == 0);
                    }
                }
            }
            if (count < ROIS) {
                for (int Wp = 4; Wp < 32 && count < ROIS; ++Wp) {
                    const int cLo = 128 * Wp + lane, cHi = cLo + 64;
                    float4 cL = crn[base + cLo]; float hL = ha[base + cLo];
                    float4 cH = crn[base + cHi]; float hH = ha[base + cHi];
                    u32 fLo = 1u, fHi = 1u;
                    for (int j2 = 0; j2 < count; ++j2) {
                        int pos = kept[j2];
                        float4 kc = crn[base + pos]; float kh = ha[base + pos];
                        fLo &= (u32)(!sup_pred(kc, kh, cL, hL));
                        fHi &= (u32)(!sup_pred(kc, kh, cH, hH));
                    }
                    u64 curLo0 = 0, curHi0 = 0, curHi1 = 0;
                    for (int r = 0; r < 64; ++r) {
                        float4 rc = crn[base + 128 * Wp + r]; float rh = ha[base + 128 * Wp + r];
                        curLo0 |= ((u64)(sup_pred(rc, rh, cL, hL) ? 1u : 0u)) << r;
                        curHi0 |= ((u64)(sup_pred(rc, rh, cH, hH) ? 1u : 0u)) << r;
                    }
                    for (int r = 0; r < 64; ++r) {
                        float4 rc = crn[base + 128 * Wp + 64 + r]; float rh = ha[base + 128 * Wp + 64 + r];
                        curHi1 |= ((u64)(sup_pred(rc, rh, cH, hH) ? 1u : 0u)) << r;
                    }
                    u64 availLo = __ballot(fLo != 0);
                    while (availLo != 0 && count < ROIS) {
                        int r = __builtin_ctzll(availLo);
                        if (lane == 0) kept[count] = Wp * 128 + r;
                        ++count;
                        fLo &= (u32)(((curLo0 >> r) & 1ULL) ^ 1ULL) & (u32)(lane != r);
                        fHi &= (u32)(((curHi0 >> r) & 1ULL) ^ 1ULL);
                        availLo = __ballot(fLo != 0);
                    }
                    u64 availHi = __ballot(fHi != 0);
                    while (availHi != 0 && count < ROIS) {
                        int r = __builtin_ctzll(availHi);
                        if (lane == 0) kept[count] = Wp * 128 + 64 + r;
                        ++count;
                        fHi &= (u32)(((curHi1 >> r) & 1ULL) ^ 1ULL) & (u32)(lane != r);
                        availHi = __ballot(fHi != 0);
                    }
                }
            }
        }
        __syncthreads();
        if (t < ROIS) {
            int pos = kept[t];
            int orig = (int)sortedIdx[base + pos];
            const float* bp = in + (base + orig) * 5;
            ((float4*)outp)[(size_t)b * ROIS + t] =
                make_float4(bp[1], bp[2], bp[3], bp[4]);
        }
    }
}

// K2: 72 half-word h-tasks over 18 blocks x 4 waves (1 task/wave); the
// last-arriving block (device-scope atomic) runs the scan + output.
__global__ __launch_bounds__(256, 1) void nms_k2(
        const float* __restrict__ in, const float4* __restrict__ crn512,
        const float* __restrict__ ha512, const u32* __restrict__ sidx512,
        const int* __restrict__ flag, int* __restrict__ done,
        int* __restrict__ needFull, u64* __restrict__ hbuf,
        float* __restrict__ outp) {
    const int b = blockIdx.y, blk = blockIdx.x;   // blk 0..17
    if (flag[b]) return;                          // uniform; K1 handled batch
    __shared__ float4 crn_s[512];
    __shared__ float  ha_s[512];
    __shared__ u64    h_lds[2304];
    __shared__ int    kept[ROIS];
    __shared__ int    s_last, s_need;
    const int t = threadIdx.x, lane = t & 63, wid = t >> 6;

    for (int i = t; i < 512; i += 256) {          // stage 512 boxes
        crn_s[i] = crn512[(size_t)b * 512 + i];
        ha_s[i]  = ha512[(size_t)b * 512 + i];
    }
    __syncthreads();

    {   // one task per wave: tau = blk*4 + wid in 0..71, each exactly once
        int tau = blk * 4 + wid;
        int u = tau >> 1, hf = tau & 1;
        int kr = 0;
        while ((kr + 1) * (kr + 2) / 2 <= u) ++kr;
        int w = u - kr * (kr + 1) / 2;
        float4 myc = crn_s[64 * kr + lane];
        float  myh = ha_s[64 * kr + lane];
        u32 word = 0;
        const int q0 = hf * 32;
        #pragma unroll 8
        for (int q = 0; q < 32; ++q) {            // uniform -> LDS broadcast
            bool p = sup_pred(crn_s[64 * w + q0 + q], ha_s[64 * w + q0 + q], myc, myh);
            word |= (u32)(p ? 1u : 0u) << q;
        }
        ((u32*)hbuf)[(((size_t)b * 36 + u) * 64 + lane) * 2 + hf] = word;
    }

    __threadfence();                              // release own h-writes (device)
    __syncthreads();
    if (t == 0) { int old = atomicAdd(&done[b], 1); s_last = (old == 17); }
    __syncthreads();
    if (!s_last) return;
    __threadfence();                              // acquire before reading h

    for (int i = t; i < 2304; i += 256) h_lds[i] = hbuf[(size_t)b * 2304 + i];
    for (int r = t; r < ROIS; r += 256) kept[r] = 0;
    if (t == 0) s_need = 0;
    __syncthreads();

    if (t < 64) {                                 // scalar-chain scan, kb-expansion
        int count = 0;
        u32 f[8];
        #pragma unroll
        for (int k = 0; k < 8; ++k) f[k] = 1u;
        bool done_ = false;
        #pragma unroll
        for (int g = 0; g < 8; ++g) {
            if (!done_) {
                u64 hgg = h_lds[(g * (g + 1) / 2 + g) * 64 + lane];
                u64 kb = 0;
                const int gbase = count;
                u64 avail = __ballot(f[g] != 0);  // one ballot per group
                while (avail != 0 && count < ROIS) {
                    int r = __builtin_ctzll(avail);       // wave-uniform
                    kb |= 1ULL << r;
                    ++count;
                    u64 w = rdlane_u64(hgg, r);   // symmetry: col r's word
                    avail &= ~(w | (1ULL << r));
                }
                // expansion: ctz takes ascending r -> prefix-popcount = order
                if ((kb >> lane) & 1ULL)
                    kept[gbase + (int)__popcll(kb & ((1ULL << lane) - 1ULL))] = g * 64 + lane;
                if (count >= ROIS) {
                    done_ = true;
                } else {
                    #pragma unroll
                    for (int k2 = g + 1; k2 < 8; ++k2)
                        f[k2] &= (u32)((h_lds[(k2 * (k2 + 1) / 2 + g) * 64 + lane] & kb) == 0);
                }
            }
        }
        if (t == 0) s_need = (count >= ROIS) ? 0 : 1;
    }
    __syncthreads();

    if (s_need) { if (t == 0) needFull[b] = 1; return; }   // K3 finishes batch

    if (t < ROIS) {
        int pos = kept[t];
        int orig = (int)sidx512[(size_t)b * 512 + pos];
        const float* bp = in + ((size_t)b * NMS_N + orig) * 5;
        ((float4*)outp)[(size_t)b * ROIS + t] =
            make_float4(bp[1], bp[2], bp[3], bp[4]);
    }
}

// K3: fallback-only (no-op unless scan found <256 within 512 rows).
__global__ __launch_bounds__(1024, 1) void nms_k3(
        const float* __restrict__ in, const int* __restrict__ needFull,
        u32* __restrict__ sortedIdx, float4* __restrict__ crn,
        float* __restrict__ ha, float* __restrict__ outp) {
    __shared__ u64 sm[5120];
    __shared__ int kept[ROIS];
    const int b = blockIdx.x, t = threadIdx.x;
    const int lane = t & 63, wid = t >> 6;
    const size_t base = (size_t)b * NMS_N;
    if (!needFull[b]) return;                     // uniform fast exit

    // full v8 path (verbatim)
    u64 key[4];
    #pragma unroll
    for (int r = 0; r < 4; ++r) {
        int e = 4 * t + r;
        float s = in[(base + e) * 5];
        key[r] = ((u64)(~__float_as_uint(s)) << 32) | (u32)e;
    }
    for (int k = 2; k <= 4096; k <<= 1) {
        int j = k >> 1;
        if (j >= 256) {
            #pragma unroll
            for (int r = 0; r < 4; ++r) sm[lds_slot(4 * t + r)] = key[r];
            __syncthreads();
            for (; j >= 256; j >>= 1) {
                for (int el = t; el < 4096; el += 1024) {
                    int p = el ^ j;
                    if (p > el) {
                        u64 a = sm[lds_slot(el)], cc = sm[lds_slot(p)];
                        bool up = ((el & k) == 0);
                        if ((a > cc) == up) { sm[lds_slot(el)] = cc; sm[lds_slot(p)] = a; }
                    }
                }
                __syncthreads();
            }
            #pragma unroll
            for (int r = 0; r < 4; ++r) key[r] = sm[lds_slot(4 * t + r)];
        }
        for (; j >= 4; j >>= 1) {
            int d = j >> 2;
            #pragma unroll
            for (int r = 0; r < 4; ++r) {
                int e = 4 * t + r;
                u64 mine = key[r];
                u64 part = __shfl_xor(mine, d, 64);
                bool up = ((e & k) == 0);
                bool lower = ((e & j) == 0);
                u64 mn = (mine < part) ? mine : part;
                u64 mx = (mine < part) ? part : mine;
                key[r] = (up == lower) ? mn : mx;
            }
        }
        for (; j >= 1; j >>= 1) {
            #pragma unroll
            for (int r = 0; r < 4; ++r) {
                int pr = r | j;
                if (((r & j) == 0) && pr < 4) {
                    int e = 4 * t + r;
                    bool up = ((e & k) == 0);
                    u64 a = key[r], cc = key[pr];
                    if ((a > cc) == up) { key[r] = cc; key[pr] = a; }
                }
            }
        }
    }
    __syncthreads();

    u64*    h2 = sm;                      // [36][64]
    float4* crn2 = (float4*)(sm + 2304);  // [512]
    float*  ha2  = (float*)(sm + 2304 + 1024);

    #pragma unroll
    for (int r = 0; r < 4; ++r) {
        int e = 4 * t + r;
        u32 orig = (u32)key[r];
        const float* bp = in + (base + orig) * 5;
        float x = bp[1], y = bp[2], w = bp[3], h = bp[4];
        float ws_ = floorf(w * 0.5f), hs_ = floorf(h * 0.5f);
        float4 c4 = make_float4(x - ws_, y - hs_, x + ws_, y + hs_);
        float hv = 0.5f * ((c4.z - c4.x) * (c4.w - c4.y));
        size_t g = base + e;
        sortedIdx[g] = orig;
        crn[g] = c4;
        ha[g] = hv;
        if (e < 512) { crn2[e] = c4; ha2[e] = hv; }
    }
    for (int r = t; r < ROIS; r += 1024) kept[r] = 0;
    __syncthreads();

    for (int u = wid; u < 36; u += 16) {
        int kr = 0;
        while ((kr + 1) * (kr + 2) / 2 <= u) ++kr;
        int w = u - kr * (kr + 1) / 2;
        float4 myc = crn2[64 * kr + lane];
        float  myh = ha2[64 * kr + lane];
        u64 word = 0;
        #pragma unroll 4
        for (int q = 0; q < 64; ++q) {
            bool p = sup_pred(crn2[64 * w + q], ha2[64 * w + q], myc, myh);
            word |= ((u64)(p ? 1u : 0u)) << q;
        }
        h2[(size_t)u * 64 + lane] = word;
    }
    __syncthreads();

    if (t < 64) {
        int count = 0;
        u32 f[8];
        #pragma unroll
        for (int k = 0; k < 8; ++k) f[k] = 1u;
        bool done_ = false;
        #pragma unroll
        for (int g = 0; g < 8; ++g) {
            if (!done_) {
                u64 hgg = h2[(size_t)(g * (g + 1) / 2 + g) * 64 + lane];
                u64 kb = 0;
                u64 avail = __ballot(f[g] != 0);
                while (avail != 0 && count < ROIS) {
                    int r = __builtin_ctzll(avail);
                    if (lane == 0) kept[count] = g * 64 + r;
                    ++count;
                    kb |= 1ULL << r;
                    u32 bit = (u32)(hgg >> r) & 1u;
                    f[g] &= (bit ^ 1u) & (u32)(lane != r);
                    avail = __ballot(f[g] != 0);
                }
                if (count >= ROIS) {
                    done_ = true;
                } else {
                    #pragma unroll
                    for (int k2 = g + 1; k2 < 8; ++k2)
                        f[k2] &= (u32)((h2[(size_t)(k2 * (k2 + 1) / 2 + g) * 64 + lane] & kb) == 0);
                }
            }
        }
        if (count < ROIS) {
            for (int Wp = 4; Wp < 32 && count < ROIS; ++Wp) {
                const int cLo = 128 * Wp + lane, cHi = cLo + 64;
                float4 cL = crn[base + cLo]; float hL = ha[base + cLo];
                float4 cH = crn[base + cHi]; float hH = ha[base + cHi];
                u32 fLo = 1u, fHi = 1u;
                for (int j2 = 0; j2 < count; ++j2) {
                    int pos = kept[j2];
                    float4 kc = crn[base + pos]; float kh = ha[base + pos];
                    fLo &= (u32)(!sup_pred(kc, kh, cL, hL));
                    fHi &= (u32)(!sup_pred(kc, kh, cH, hH));
                }
                u64 curLo0 = 0, curHi0 = 0, curHi1 = 0;
                for (int r = 0; r < 64; ++r) {
                    float4 rc = crn[base + 128 * Wp + r]; float rh = ha[base + 128 * Wp + r];
                    curLo0 |= ((u64)(sup_pred(rc, rh, cL, hL) ? 1u : 0u)) << r;
                    curHi0 |= ((u64)(sup_pred(rc, rh, cH, hH) ? 1u : 0u)) << r;
                }
                for (int r = 0; r < 64; ++r) {
                    float4 rc = crn[base + 128 * Wp + 64 + r]; float rh = ha[base + 128 * Wp + 64 + r];
                    curHi1 |= ((u64)(sup_pred(rc, rh, cH, hH) ? 1u : 0u)) << r;
                }
                u64 availLo = __ballot(fLo != 0);
                while (availLo != 0 && count < ROIS) {
                    int r = __builtin_ctzll(availLo);
                    if (lane == 0) kept[count] = Wp * 128 + r;
                    ++count;
                    fLo &= (u32)(((curLo0 >> r) & 1ULL) ^ 1ULL) & (u32)(lane != r);
                    fHi &= (u32)(((curHi0 >> r) & 1ULL) ^ 1ULL);
                    availLo = __ballot(fLo != 0);
                }
                u64 availHi = __ballot(fHi != 0);
                while (availHi != 0 && count < ROIS) {
                    int r = __builtin_ctzll(availHi);
                    if (lane == 0) kept[count] = Wp * 128 + 64 + r;
                    ++count;
                    fHi &= (u32)(((curHi1 >> r) & 1ULL) ^ 1ULL) & (u32)(lane != r);
                    availHi = __ballot(fHi != 0);
                }
            }
        }
    }
    __syncthreads();

    if (t < ROIS) {
        int pos = kept[t];
        int orig = (int)sortedIdx[base + pos];
        const float* bp = in + (base + orig) * 5;
        ((float4*)outp)[(size_t)b * ROIS + t] =
            make_float4(bp[1], bp[2], bp[3], bp[4]);
    }
}

extern "C" void kernel_launch(void* const* d_in, const int* in_sizes, int n_in,
                              void* d_out, int out_size, void* d_ws, size_t ws_size,
                              hipStream_t stream) {
    const float* in = (const float*)d_in[0];
    float* out = (float*)d_out;
    char* ws = (char*)d_ws;

    u32* sortedIdx = (u32*)ws;                  size_t off = (size_t)NMS_B * NMS_N * 4;
    float4* crn = (float4*)(ws + off);          off += (size_t)NMS_B * NMS_N * 16;
    float* ha = (float*)(ws + off);             off += (size_t)NMS_B * NMS_N * 4;
    float4* crn512 = (float4*)(ws + off);       off += (size_t)NMS_B * 512 * 16;
    float* ha512 = (float*)(ws + off);          off += (size_t)NMS_B * 512 * 4;
    u32* sidx512 = (u32*)(ws + off);            off += (size_t)NMS_B * 512 * 4;
    u64* hbuf = (u64*)(ws + off);               off += (size_t)NMS_B * 36 * 64 * 8;
    int* flag = (int*)(ws + off);               off += NMS_B * 4;
    int* done = (int*)(ws + off);               off += NMS_B * 4;
    int* needFull = (int*)(ws + off);           off += NMS_B * 4;

    nms_k1<<<NMS_B, 1024, 0, stream>>>(in, crn512, ha512, sidx512, flag, done,
                                       needFull, sortedIdx, crn, ha, out);
    nms_k2<<<dim3(18, NMS_B), 256, 0, stream>>>(in, crn512, ha512, sidx512,
                                                flag, done, needFull, hbuf, out);
    nms_k3<<<NMS_B, 1024, 0, stream>>>(in, needFull, sortedIdx, crn, ha, out);
}

// Round 14
// 83.969 us; speedup vs baseline: 1.1724x; 1.1724x over previous
//
#include <hip/hip_runtime.h>
#include <stdint.h>

#pragma clang fp contract(off)

#define NMS_B 8
#define NMS_N 4096
#define ROIS 256
#define SEL_TAU 0.85f

typedef unsigned long long u64;
typedef unsigned int u32;

__device__ __forceinline__ int lds_slot(int e) { return e + (e >> 2); }  // 4-way max bank aliasing

__device__ __forceinline__ u64 rdlane_u64(u64 v, int l) {
    u32 lo = (u32)__builtin_amdgcn_readlane((int)(u32)v, l);
    u32 hi = (u32)__builtin_amdgcn_readlane((int)(u32)(v >> 32), l);
    return ((u64)hi << 32) | lo;
}

// suppression predicate (exact arithmetic of the proven K2):
// true => row box suppresses col box (IoU > 0.5); symmetric.
__device__ __forceinline__ bool sup_pred(float4 rc, float rh, float4 cc, float ch) {
    float iw = fmaxf(fminf(rc.z, cc.z) - fmaxf(rc.x, cc.x), 0.0f);
    float ih = fmaxf(fminf(rc.w, cc.w) - fmaxf(rc.y, cc.y), 0.0f);
    float inter = iw * ih;
    return inter > fmaf(-0.5f, inter, rh + ch);   // 1.5*inter > haR+haC
}

// ---------------------------------------------------------------------------
// v16 = v14 skeleton (launch-boundary sync; v15's mid-kernel threadfence
// caused buffer_wbl2 L2-flush storms: K2 5->42us) + two clean grafts:
//  (a) K2: 18 blocks x 4 waves x 1 task (halves per-wave E work; no sync).
//  (b) K3 scan: kept-recording via kb bitmap + popcount-prefix expansion
//      after the group loop (bit-identical: ctz takes ascending r).
// ---------------------------------------------------------------------------

// K1: select (tau) + bitonic-1024 + corners for top-512 -> workspace.
__global__ __launch_bounds__(1024, 1) void nms_k1(
        const float* __restrict__ in, float4* __restrict__ crn512,
        float* __restrict__ ha512, u32* __restrict__ sidx512,
        int* __restrict__ flag) {
    __shared__ u64 sm[3584];                 // selKey 1024 | sortA0 1280 | sortA1 1280
    __shared__ int s_selCount;
    const int b = blockIdx.x, t = threadIdx.x;
    const int lane = t & 63;
    const size_t base = (size_t)b * NMS_N;

    u64* selKey = sm;
    u64* sortA0 = sm + 1024;
    u64* sortA1 = sm + 2304;

    // A: load scores
    float sc[4];
    #pragma unroll
    for (int r = 0; r < 4; ++r) {
        int e = t + 1024 * r;
        sc[r] = in[(base + e) * 5];
    }
    if (t == 0) s_selCount = 0;
    __syncthreads();

    // B: wave-aggregated selection append (score >= tau)
    #pragma unroll
    for (int r = 0; r < 4; ++r) {
        bool pred = (sc[r] >= SEL_TAU);
        u64 m = __ballot(pred);
        u32 cnt = (u32)__popcll(m);
        int wbase = 0;
        if (lane == 0 && cnt) wbase = atomicAdd(&s_selCount, (int)cnt);
        wbase = __shfl(wbase, 0, 64);
        if (pred) {
            int slot = wbase + (int)__popcll(m & ((1ULL << lane) - 1ULL));
            if (slot < 1024) {
                int e = t + 1024 * r;
                selKey[slot] = ((u64)(~__float_as_uint(sc[r])) << 32) | (u32)e;
            }
        }
    }
    __syncthreads();
    const int selCount = s_selCount;
    const bool fullPath = (selCount < 512) || (selCount > 1024);   // uniform
    if (t == 0) flag[b] = fullPath ? 1 : 0;
    if (fullPath) return;                    // K3 does the exact full path

    // C: bitonic 1024, 1 elem/thread, double-buffered LDS (bit-identical)
    u64 kk = (t < selCount) ? selKey[t] : ~0ULL;   // pad sorts to end
    int s = 0;
    for (int k = 2; k <= 1024; k <<= 1) {
        int j = k >> 1;
        for (; j >= 64; j >>= 1) {
            u64* buf = s ? sortA1 : sortA0;
            buf[lds_slot(t)] = kk;
            __syncthreads();                 // RAW only; WAR killed by dbuf
            u64 part = buf[lds_slot(t ^ j)];
            bool up = ((t & k) == 0), lower = ((t & j) == 0);
            u64 mn = kk < part ? kk : part, mx = kk < part ? part : kk;
            kk = (up == lower) ? mn : mx;
            s ^= 1;
        }
        for (; j >= 1; j >>= 1) {
            u64 part = __shfl_xor(kk, j, 64);
            bool up = ((t & k) == 0), lower = ((t & j) == 0);
            u64 mn = kk < part ? kk : part, mx = kk < part ? part : kk;
            kk = (up == lower) ? mn : mx;
        }
    }
    // thread t holds sorted element t

    // D: corners for top-512 -> workspace (coalesced stores)
    if (t < 512) {
        u32 orig = (u32)kk;
        const float* bp = in + (base + orig) * 5;
        float x = bp[1], y = bp[2], w = bp[3], h = bp[4];
        float ws_ = floorf(w * 0.5f), hs_ = floorf(h * 0.5f);
        float4 c4 = make_float4(x - ws_, y - hs_, x + ws_, y + hs_);
        size_t g = (size_t)b * 512 + t;
        crn512[g] = c4;
        ha512[g] = 0.5f * ((c4.z - c4.x) * (c4.w - c4.y));  // exact half-area
        sidx512[g] = orig;
    }
}

// K2: 72 half-word h-tasks over 18 blocks x 4 waves (1 task/wave).
// No cross-block sync; the K2->K3 launch boundary provides coherence.
__global__ __launch_bounds__(256, 1) void nms_k2(
        const float4* __restrict__ crn512, const float* __restrict__ ha512,
        const int* __restrict__ flag, u64* __restrict__ hbuf) {
    const int b = blockIdx.y, blk = blockIdx.x;   // blk 0..17
    if (flag[b]) return;                          // uniform; K3 handles batch
    __shared__ float4 crn_s[512];
    __shared__ float  ha_s[512];
    const int t = threadIdx.x, lane = t & 63, wid = t >> 6;

    for (int i = t; i < 512; i += 256) {          // stage 512 boxes
        crn_s[i] = crn512[(size_t)b * 512 + i];
        ha_s[i]  = ha512[(size_t)b * 512 + i];
    }
    __syncthreads();

    // one task per wave: tau = blk*4 + wid in 0..71, each exactly once
    int tau = blk * 4 + wid;
    int u = tau >> 1, hf = tau & 1;
    int kr = 0;
    while ((kr + 1) * (kr + 2) / 2 <= u) ++kr;
    int w = u - kr * (kr + 1) / 2;
    float4 myc = crn_s[64 * kr + lane];
    float  myh = ha_s[64 * kr + lane];
    u32 word = 0;
    const int q0 = hf * 32;
    #pragma unroll 8
    for (int q = 0; q < 32; ++q) {                // uniform -> LDS broadcast
        bool p = sup_pred(crn_s[64 * w + q0 + q], ha_s[64 * w + q0 + q], myc, myh);
        word |= (u32)(p ? 1u : 0u) << q;
    }
    ((u32*)hbuf)[(((size_t)b * 36 + u) * 64 + lane) * 2 + hf] = word;
}

// K3: stage h -> LDS, wave-0 scalar-chain scan (kb-expansion), output.
// Exact v8 full fallback inside (1024 threads) for flag or scan shortfall.
__global__ __launch_bounds__(1024, 1) void nms_k3(
        const float* __restrict__ in, const u32* __restrict__ sidx512,
        const u64* __restrict__ hbuf, const int* __restrict__ flag,
        u32* __restrict__ sortedIdx, float4* __restrict__ crn,
        float* __restrict__ ha, float* __restrict__ outp) {
    __shared__ u64 sm[5120];                 // h_lds [2304] (fast) / v8 arena (full)
    __shared__ int kept[ROIS];
    __shared__ int s_need;
    const int b = blockIdx.x, t = threadIdx.x;
    const int lane = t & 63, wid = t >> 6;
    const size_t base = (size_t)b * NMS_N;

    int flg = flag[b];                       // uniform
    if (!flg) {
        for (int i = t; i < 2304; i += 1024) sm[i] = hbuf[(size_t)b * 2304 + i];
        for (int r = t; r < ROIS; r += 1024) kept[r] = 0;
        if (t == 0) s_need = 0;
        __syncthreads();

        if (t < 64) {                        // wave-0 scalar-chain scan
            u64* h_lds = sm;                 // h_lds[u*64+lane]
            int count = 0;
            u32 f[8];
            #pragma unroll
            for (int k = 0; k < 8; ++k) f[k] = 1u;
            bool done = false;
            #pragma unroll
            for (int g = 0; g < 8; ++g) {
                if (!done) {
                    u64 hgg = h_lds[(g * (g + 1) / 2 + g) * 64 + lane];
                    u64 kb = 0;
                    const int gbase = count;
                    u64 avail = __ballot(f[g] != 0);   // one ballot per group
                    while (avail != 0 && count < ROIS) {
                        int r = __builtin_ctzll(avail);        // wave-uniform
                        kb |= 1ULL << r;
                        ++count;
                        u64 w = rdlane_u64(hgg, r);    // symmetry: col r's word
                        avail &= ~(w | (1ULL << r));
                    }
                    // expansion: ctz picks ascending r -> prefix-popcount = order
                    if ((kb >> lane) & 1ULL)
                        kept[gbase + (int)__popcll(kb & ((1ULL << lane) - 1ULL))] = g * 64 + lane;
                    if (count >= ROIS) {
                        done = true;
                    } else {
                        #pragma unroll
                        for (int k2 = g + 1; k2 < 8; ++k2)
                            f[k2] &= (u32)((h_lds[(k2 * (k2 + 1) / 2 + g) * 64 + lane] & kb) == 0);
                    }
                }
            }
            if (t == 0) s_need = (count >= ROIS) ? 0 : 1;
        }
        __syncthreads();
        flg = s_need;                        // uniform via LDS
    }

    // ======== FULL FALLBACK (correctness-only; never on bench data) ========
    if (flg) {
        // P1: full 4096 bitonic sort (v8 verbatim)
        u64 key[4];
        #pragma unroll
        for (int r = 0; r < 4; ++r) {
            int e = 4 * t + r;
            float s = in[(base + e) * 5];
            key[r] = ((u64)(~__float_as_uint(s)) << 32) | (u32)e;
        }
        for (int k = 2; k <= 4096; k <<= 1) {
            int j = k >> 1;
            if (j >= 256) {
                #pragma unroll
                for (int r = 0; r < 4; ++r) sm[lds_slot(4 * t + r)] = key[r];
                __syncthreads();
                for (; j >= 256; j >>= 1) {
                    for (int el = t; el < 4096; el += 1024) {
                        int p = el ^ j;
                        if (p > el) {
                            u64 a = sm[lds_slot(el)], cc = sm[lds_slot(p)];
                            bool up = ((el & k) == 0);
                            if ((a > cc) == up) { sm[lds_slot(el)] = cc; sm[lds_slot(p)] = a; }
                        }
                    }
                    __syncthreads();
                }
                #pragma unroll
                for (int r = 0; r < 4; ++r) key[r] = sm[lds_slot(4 * t + r)];
            }
            for (; j >= 4; j >>= 1) {
                int d = j >> 2;
                #pragma unroll
                for (int r = 0; r < 4; ++r) {
                    int e = 4 * t + r;
                    u64 mine = key[r];
                    u64 part = __shfl_xor(mine, d, 64);
                    bool up = ((e & k) == 0);
                    bool lower = ((e & j) == 0);
                    u64 mn = (mine < part) ? mine : part;
                    u64 mx = (mine < part) ? part : mine;
                    key[r] = (up == lower) ? mn : mx;
                }
            }
            for (; j >= 1; j >>= 1) {
                #pragma unroll
                for (int r = 0; r < 4; ++r) {
                    int pr = r | j;
                    if (((r & j) == 0) && pr < 4) {
                        int e = 4 * t + r;
                        bool up = ((e & k) == 0);
                        u64 a = key[r], cc = key[pr];
                        if ((a > cc) == up) { key[r] = cc; key[pr] = a; }
                    }
                }
            }
        }
        __syncthreads();

        u64*    h2 = sm;                      // [36][64]
        float4* crn2 = (float4*)(sm + 2304);  // [512]
        float*  ha2  = (float*)(sm + 2304 + 1024);

        // P2
        #pragma unroll
        for (int r = 0; r < 4; ++r) {
            int e = 4 * t + r;
            u32 orig = (u32)key[r];
            const float* bp = in + (base + orig) * 5;
            float x = bp[1], y = bp[2], w = bp[3], h = bp[4];
            float ws_ = floorf(w * 0.5f), hs_ = floorf(h * 0.5f);
            float4 c4 = make_float4(x - ws_, y - hs_, x + ws_, y + hs_);
            float hv = 0.5f * ((c4.z - c4.x) * (c4.w - c4.y));
            size_t g = base + e;
            sortedIdx[g] = orig;
            crn[g] = c4;
            ha[g] = hv;
            if (e < 512) { crn2[e] = c4; ha2[e] = hv; }
        }
        for (int r = t; r < ROIS; r += 1024) kept[r] = 0;
        __syncthreads();

        // P3
        for (int u = wid; u < 36; u += 16) {
            int kr = 0;
            while ((kr + 1) * (kr + 2) / 2 <= u) ++kr;
            int w = u - kr * (kr + 1) / 2;
            float4 myc = crn2[64 * kr + lane];
            float  myh = ha2[64 * kr + lane];
            u64 word = 0;
            #pragma unroll 4
            for (int q = 0; q < 64; ++q) {
                bool p = sup_pred(crn2[64 * w + q], ha2[64 * w + q], myc, myh);
                word |= ((u64)(p ? 1u : 0u)) << q;
            }
            h2[(size_t)u * 64 + lane] = word;
        }
        __syncthreads();

        // P4+P5
        if (t < 64) {
            int count = 0;
            u32 f[8];
            #pragma unroll
            for (int k = 0; k < 8; ++k) f[k] = 1u;
            bool done = false;
            #pragma unroll
            for (int g = 0; g < 8; ++g) {
                if (!done) {
                    u64 hgg = h2[(size_t)(g * (g + 1) / 2 + g) * 64 + lane];
                    u64 kb = 0;
                    u64 avail = __ballot(f[g] != 0);
                    while (avail != 0 && count < ROIS) {
                        int r = __builtin_ctzll(avail);
                        if (lane == 0) kept[count] = g * 64 + r;
                        ++count;
                        kb |= 1ULL << r;
                        u32 bit = (u32)(hgg >> r) & 1u;
                        f[g] &= (bit ^ 1u) & (u32)(lane != r);
                        avail = __ballot(f[g] != 0);
                    }
                    if (count >= ROIS) {
                        done = true;
                    } else {
                        #pragma unroll
                        for (int k2 = g + 1; k2 < 8; ++k2)
                            f[k2] &= (u32)((h2[(size_t)(k2 * (k2 + 1) / 2 + g) * 64 + lane] & kb) == 0);
                    }
                }
            }
            if (count < ROIS) {
                for (int Wp = 4; Wp < 32 && count < ROIS; ++Wp) {
                    const int cLo = 128 * Wp + lane, cHi = cLo + 64;
                    float4 cL = crn[base + cLo]; float hL = ha[base + cLo];
                    float4 cH = crn[base + cHi]; float hH = ha[base + cHi];
                    u32 fLo = 1u, fHi = 1u;
                    for (int j2 = 0; j2 < count; ++j2) {
                        int pos = kept[j2];
                        float4 kc = crn[base + pos]; float kh = ha[base + pos];
                        fLo &= (u32)(!sup_pred(kc, kh, cL, hL));
                        fHi &= (u32)(!sup_pred(kc, kh, cH, hH));
                    }
                    u64 curLo0 = 0, curHi0 = 0, curHi1 = 0;
                    for (int r = 0; r < 64; ++r) {
                        float4 rc = crn[base + 128 * Wp + r]; float rh = ha[base + 128 * Wp + r];
                        curLo0 |= ((u64)(sup_pred(rc, rh, cL, hL) ? 1u : 0u)) << r;
                        curHi0 |= ((u64)(sup_pred(rc, rh, cH, hH) ? 1u : 0u)) << r;
                    }
                    for (int r = 0; r < 64; ++r) {
                        float4 rc = crn[base + 128 * Wp + 64 + r]; float rh = ha[base + 128 * Wp + 64 + r];
                        curHi1 |= ((u64)(sup_pred(rc, rh, cH, hH) ? 1u : 0u)) << r;
                    }
                    u64 availLo = __ballot(fLo != 0);
                    while (availLo != 0 && count < ROIS) {
                        int r = __builtin_ctzll(availLo);
                        if (lane == 0) kept[count] = Wp * 128 + r;
                        ++count;
                        fLo &= (u32)(((curLo0 >> r) & 1ULL) ^ 1ULL) & (u32)(lane != r);
                        fHi &= (u32)(((curHi0 >> r) & 1ULL) ^ 1ULL);
                        availLo = __ballot(fLo != 0);
                    }
                    u64 availHi = __ballot(fHi != 0);
                    while (availHi != 0 && count < ROIS) {
                        int r = __builtin_ctzll(availHi);
                        if (lane == 0) kept[count] = Wp * 128 + 64 + r;
                        ++count;
                        fHi &= (u32)(((curHi1 >> r) & 1ULL) ^ 1ULL) & (u32)(lane != r);
                        availHi = __ballot(fHi != 0);
                    }
                }
            }
        }
    }
    __syncthreads();

    // ---- output ----
    if (t < ROIS) {
        int pos = kept[t];
        int orig = flg ? (int)sortedIdx[base + pos]
                       : (int)sidx512[(size_t)b * 512 + pos];
        const float* bp = in + (base + orig) * 5;
        ((float4*)outp)[(size_t)b * ROIS + t] =
            make_float4(bp[1], bp[2], bp[3], bp[4]);
    }
}

extern "C" void kernel_launch(void* const* d_in, const int* in_sizes, int n_in,
                              void* d_out, int out_size, void* d_ws, size_t ws_size,
                              hipStream_t stream) {
    const float* in = (const float*)d_in[0];
    float* out = (float*)d_out;
    char* ws = (char*)d_ws;

    u32* sortedIdx = (u32*)ws;                  size_t off = (size_t)NMS_B * NMS_N * 4;
    float4* crn = (float4*)(ws + off);          off += (size_t)NMS_B * NMS_N * 16;
    float* ha = (float*)(ws + off);             off += (size_t)NMS_B * NMS_N * 4;
    float4* crn512 = (float4*)(ws + off);       off += (size_t)NMS_B * 512 * 16;
    float* ha512 = (float*)(ws + off);          off += (size_t)NMS_B * 512 * 4;
    u32* sidx512 = (u32*)(ws + off);            off += (size_t)NMS_B * 512 * 4;
    u64* hbuf = (u64*)(ws + off);               off += (size_t)NMS_B * 36 * 64 * 8;
    int* flag = (int*)(ws + off);               off += NMS_B * 4;

    nms_k1<<<NMS_B, 1024, 0, stream>>>(in, crn512, ha512, sidx512, flag);
    nms_k2<<<dim3(18, NMS_B), 256, 0, stream>>>(crn512, ha512, flag, hbuf);
    nms_k3<<<NMS_B, 1024, 0, stream>>>(in, sidx512, hbuf, flag, sortedIdx, crn, ha, out);
}